// Round 3
// baseline (573.199 us; speedup 1.0000x reference)
//
#include <hip/hip_runtime.h>
#include <hip/hip_bf16.h>

// MDTA: qkv 1x1 conv -> 3x3 depthwise -> l2norm(q,k) -> spatial cosine
// attention (flash, MFMA bf16) -> 1x1 proj.
// Input/output dtype resolved AT RUNTIME by a probe kernel (fp32 vs bf16):
// every dtype-dependent kernel is launched in both variants, guarded by a
// flag in d_ws. Intermediates are bf16 in d_ws.

#define BB 2
#define CCH 192
#define C3 576
#define NH 4
#define HD 48
#define NP 4096

typedef __hip_bfloat16 bf16;
typedef __attribute__((ext_vector_type(8))) short bf16x8;
typedef __attribute__((ext_vector_type(4))) float f32x4;

__device__ inline float bf2f(bf16 v){ return __bfloat162float(v); }
__device__ inline unsigned short bfbits(bf16 v){ return __builtin_bit_cast(unsigned short, v); }
__device__ inline unsigned short f2bfbits(float f){ return __builtin_bit_cast(unsigned short, __float2bfloat16(f)); }
__device__ inline unsigned xbits(bf16 v){ return (unsigned)bfbits(v); }
__device__ inline unsigned xbits(float v){ return (unsigned)f2bfbits(v); }
__device__ inline float ldf(const bf16* p){ return bf2f(*p); }
__device__ inline float ldf(const float* p){ return *p; }
__device__ inline void stf(bf16* p, float v){ *p = __float2bfloat16(v); }
__device__ inline void stf(float* p, float v){ *p = v; }
__device__ inline float2 unpack2(unsigned u){
  float2 r; r.x = __uint_as_float(u << 16); r.y = __uint_as_float(u & 0xffff0000u); return r;
}

// ---------------------------------------------------------------------------
// Probe: decide if d_in[0] holds bf16 (flag=1) or fp32 (flag=0) data.
// For bf16 data the low short of each dword is a bf16 value with a sane
// exponent (~100% of words). For fp32 data it is random mantissa bits
// (~16% sane). Threshold 75%.
// ---------------------------------------------------------------------------
__global__ void probe_kernel(const unsigned* __restrict__ x, int* __restrict__ flag)
{
  int t = threadIdx.x;           // 256 threads, 1 block
  unsigned u = x[t];
  int e = (u >> 7) & 0xff;
  int sane = (e >= 100 && e <= 140) || ((u & 0x7fffu) == 0u);
  __shared__ int cnt;
  if (t == 0) cnt = 0;
  __syncthreads();
  if (sane) atomicAdd(&cnt, 1);
  __syncthreads();
  if (t == 0) *flag = (cnt >= 192) ? 1 : 0;
}

// ---------------------------------------------------------------------------
// Convert all weights/biases/temperature to canonical bf16. Dual-dtype,
// flag-guarded.  Segment offsets in canon (elements):
//   w_qkv 0..110592, b_qkv ..111168, w_dw ..116352, b_dw ..116928,
//   w_proj ..153792, b_proj ..153984, temp ..153988
// ---------------------------------------------------------------------------
#define NCANON 153988
template<typename TI>
__global__ __launch_bounds__(256) void convert_params_kernel(
    const int* __restrict__ flag, int want,
    const void* w_qkv, const void* b_qkv, const void* w_dw, const void* b_dw,
    const void* w_proj, const void* b_proj, const void* temp,
    bf16* __restrict__ canon)
{
  if (*flag != want) return;
  int i = blockIdx.x*256 + threadIdx.x;
  if (i >= NCANON) return;
  const void* src; int off;
  if      (i < 110592){ src = w_qkv;  off = i; }
  else if (i < 111168){ src = b_qkv;  off = i - 110592; }
  else if (i < 116352){ src = w_dw;   off = i - 111168; }
  else if (i < 116928){ src = b_dw;   off = i - 116352; }
  else if (i < 153792){ src = w_proj; off = i - 116928; }
  else if (i < 153984){ src = b_proj; off = i - 153792; }
  else                { src = temp;   off = i - 153984; }
  canon[i] = __float2bfloat16(ldf((const TI*)src + off));
}

// ---------------------------------------------------------------------------
// 1x1 conv as GEMM: Y[b][o][p] = bias[o] + sum_c W[o][c] * X[b][c][p]
// K = 192. Block: 32 o x 256 p, thread micro-tile 4o x 8p, bf16x2-packed LDS.
// Dual input dtype TX, dual output dtype TY, flag-guarded.
// ---------------------------------------------------------------------------
template<typename TX, typename TY>
__global__ __launch_bounds__(256) void conv1x1_kernel(
    const int* __restrict__ flag, int want,
    const TX* __restrict__ X, const bf16* __restrict__ Wt,
    const bf16* __restrict__ bias, TY* __restrict__ Y, int OC)
{
  if (*flag != want) return;               // wave-uniform: whole block exits
  __shared__ unsigned Xs[16][256];
  __shared__ unsigned Ws[16][32];
  const int tid = threadIdx.x;
  const int pl = tid & 31, og = tid >> 5;
  const int p0 = blockIdx.x * 256;
  const int o0 = blockIdx.y * 32;
  const TX* Xb = X + (size_t)blockIdx.z * CCH * NP;
  TY* Yb = Y + (size_t)blockIdx.z * OC * NP;

  float acc[4][8];
  for (int r=0;r<4;r++){ float bv = bf2f(bias[o0+og*4+r]); for (int j=0;j<8;j++) acc[r][j]=bv; }

  for (int kc=0; kc<6; kc++){
    __syncthreads();
    for (int i=tid; i<16*256; i+=256){
      int cc=i>>8, p=i&255, c=kc*32+cc*2;
      unsigned lo = xbits(Xb[(size_t)c*NP + p0+p]);
      unsigned hi = xbits(Xb[(size_t)(c+1)*NP + p0+p]);
      Xs[cc][p] = lo | (hi<<16);
    }
    for (int i=tid; i<16*32; i+=256){
      int cc=i>>5, o=i&31;
      const bf16* wp = Wt + (size_t)(o0+o)*CCH + kc*32 + cc*2;
      Ws[cc][o] = (unsigned)bfbits(wp[0]) | ((unsigned)bfbits(wp[1])<<16);
    }
    __syncthreads();
    #pragma unroll
    for (int cc=0; cc<16; cc++){
      float2 wv[4];
      #pragma unroll
      for (int r=0;r<4;r++) wv[r] = unpack2(Ws[cc][og*4+r]);
      #pragma unroll
      for (int j=0;j<8;j++){
        float2 xv = unpack2(Xs[cc][pl+32*j]);
        #pragma unroll
        for (int r=0;r<4;r++) acc[r][j] += wv[r].x*xv.x + wv[r].y*xv.y;
      }
    }
  }
  for (int r=0;r<4;r++)
    for (int j=0;j<8;j++)
      stf(&Yb[(size_t)(o0+og*4+r)*NP + p0 + pl + 32*j], acc[r][j]);
}

// ---------------------------------------------------------------------------
// 3x3 depthwise conv, padding 1, bf16 in/out, fp32 accumulate.
// ---------------------------------------------------------------------------
__global__ __launch_bounds__(256) void dwconv_kernel(
    const bf16* __restrict__ in, const bf16* __restrict__ w,
    const bf16* __restrict__ bias, bf16* __restrict__ out)
{
  int idx = blockIdx.x*256 + threadIdx.x;
  int pos = idx & 4095; int bc = idx >> 12; int ch = bc % C3;
  int y = pos >> 6, x = pos & 63;
  const bf16* ip = in + (size_t)bc * NP;
  float s = bf2f(bias[ch]);
  #pragma unroll
  for (int ky=0;ky<3;ky++){
    int yy = y + ky - 1; if (yy < 0 || yy > 63) continue;
    #pragma unroll
    for (int kx=0;kx<3;kx++){
      int xx = x + kx - 1; if (xx < 0 || xx > 63) continue;
      s += bf2f(w[ch*9 + ky*3 + kx]) * bf2f(ip[yy*64 + xx]);
    }
  }
  out[idx] = __float2bfloat16(s);
}

// ---------------------------------------------------------------------------
// L2 normalize q and k over head-dim (48), in place, bf16.
// ---------------------------------------------------------------------------
__global__ __launch_bounds__(256) void l2norm_kernel(bf16* __restrict__ buf)
{
  int idx = blockIdx.x*256 + threadIdx.x;   // 65536 total
  int n = idx & 4095; int t = idx >> 12;
  int head = t & 3; int qk = (t>>2)&1; int b = t>>3;
  bf16* p = buf + ((size_t)b*C3 + qk*CCH + head*HD)*NP + n;
  float ss = 0.f;
  #pragma unroll
  for (int d=0; d<HD; d++){ float v = bf2f(p[(size_t)d*NP]); ss += v*v; }
  float inv = 1.0f / fmaxf(sqrtf(ss), 1e-12f);
  #pragma unroll
  for (int d=0; d<HD; d++) p[(size_t)d*NP] = __float2bfloat16(bf2f(p[(size_t)d*NP]) * inv);
}

// ---------------------------------------------------------------------------
// Flash attention, mfma_f32_16x16x32_bf16.
// Block: 4 waves x 16 queries; keys in chunks of 32. Layouts per guide §3:
// A[m=lane&15][k=quad*8+j], B[k=quad*8+j][n=lane&15],
// C/D col=lane&15 row=quad*4+reg.  d=48 padded to 64 with zeros.
// ---------------------------------------------------------------------------
__global__ __launch_bounds__(256) void flash_kernel(
    const bf16* __restrict__ qkv, const bf16* __restrict__ temp,
    bf16* __restrict__ outp)
{
  __shared__ __align__(16) short Qs[64*72];
  __shared__ __align__(16) short Ks[32*72];
  __shared__ __align__(16) short Vs[48*40];
  __shared__ __align__(16) short Ps[4*16*40];

  const int bh = blockIdx.x;
  const int b = bh >> 2, head = bh & 3;
  const int q0 = blockIdx.y * 64;
  const int tid = threadIdx.x;
  const int wave = tid >> 6, lane = tid & 63;
  const int l16 = lane & 15, quad = lane >> 4;

  const bf16* Qp = qkv + ((size_t)b*C3 + head*HD)*NP;
  const bf16* Kp = Qp + (size_t)CCH*NP;
  const bf16* Vp = Kp + (size_t)CCH*NP;
  const float sc = bf2f(temp[head]) * 1.44269504f;

  for (int i=tid; i<64*16; i+=256) Qs[(i>>4)*72 + 48 + (i&15)] = 0;
  for (int i=tid; i<32*16; i+=256) Ks[(i>>4)*72 + 48 + (i&15)] = 0;
  for (int i=tid; i<48*64; i+=256){
    int d=i>>6, qi=i&63;
    Qs[qi*72 + d] = (short)bfbits(Qp[(size_t)d*NP + q0 + qi]);
  }
  __syncthreads();
  bf16x8 aq0 = *(const bf16x8*)&Qs[(wave*16+l16)*72 + quad*8];
  bf16x8 aq1 = *(const bf16x8*)&Qs[(wave*16+l16)*72 + 32 + quad*8];

  f32x4 O0 = {0,0,0,0}, O1 = {0,0,0,0}, O2 = {0,0,0,0};
  float m[4], l[4];
  for (int r=0;r<4;r++){ m[r] = -INFINITY; l[r] = 0.f; }

  for (int k0=0; k0<NP; k0+=32){
    __syncthreads();
    for (int i=tid; i<48*32; i+=256){
      int d=i>>5, ki=i&31;
      Ks[ki*72 + d]  = (short)bfbits(Kp[(size_t)d*NP + k0 + ki]);
      Vs[d*40 + ki]  = (short)bfbits(Vp[(size_t)d*NP + k0 + ki]);
    }
    __syncthreads();

    bf16x8 bk0a = *(const bf16x8*)&Ks[l16*72 + quad*8];
    bf16x8 bk0b = *(const bf16x8*)&Ks[l16*72 + 32 + quad*8];
    bf16x8 bk1a = *(const bf16x8*)&Ks[(16+l16)*72 + quad*8];
    bf16x8 bk1b = *(const bf16x8*)&Ks[(16+l16)*72 + 32 + quad*8];
    f32x4 s0 = {0,0,0,0}, s1 = {0,0,0,0};
    s0 = __builtin_amdgcn_mfma_f32_16x16x32_bf16(aq0, bk0a, s0, 0,0,0);
    s0 = __builtin_amdgcn_mfma_f32_16x16x32_bf16(aq1, bk0b, s0, 0,0,0);
    s1 = __builtin_amdgcn_mfma_f32_16x16x32_bf16(aq0, bk1a, s1, 0,0,0);
    s1 = __builtin_amdgcn_mfma_f32_16x16x32_bf16(aq1, bk1b, s1, 0,0,0);

    float alpha[4];
    #pragma unroll
    for (int r=0;r<4;r++){
      float a0 = s0[r]*sc, a1 = s1[r]*sc;
      float mr = fmaxf(a0, a1);
      for (int off=1; off<16; off<<=1) mr = fmaxf(mr, __shfl_xor(mr, off));
      float mn = fmaxf(m[r], mr);
      float al = exp2f(m[r] - mn);
      float p0 = exp2f(a0 - mn), p1 = exp2f(a1 - mn);
      float rs = p0 + p1;
      for (int off=1; off<16; off<<=1) rs += __shfl_xor(rs, off);
      l[r] = l[r]*al + rs;
      m[r] = mn; alpha[r] = al;
      Ps[wave*640 + (quad*4+r)*40 + l16]      = (short)f2bfbits(p0);
      Ps[wave*640 + (quad*4+r)*40 + 16 + l16] = (short)f2bfbits(p1);
    }
    #pragma unroll
    for (int r=0;r<4;r++){ O0[r]*=alpha[r]; O1[r]*=alpha[r]; O2[r]*=alpha[r]; }
    __syncthreads();

    bf16x8 ap  = *(const bf16x8*)&Ps[wave*640 + l16*40 + quad*8];
    bf16x8 bv0 = *(const bf16x8*)&Vs[l16*40 + quad*8];
    bf16x8 bv1 = *(const bf16x8*)&Vs[(16+l16)*40 + quad*8];
    bf16x8 bv2 = *(const bf16x8*)&Vs[(32+l16)*40 + quad*8];
    O0 = __builtin_amdgcn_mfma_f32_16x16x32_bf16(ap, bv0, O0, 0,0,0);
    O1 = __builtin_amdgcn_mfma_f32_16x16x32_bf16(ap, bv1, O1, 0,0,0);
    O2 = __builtin_amdgcn_mfma_f32_16x16x32_bf16(ap, bv2, O2, 0,0,0);
  }

  bf16* Ob = outp + ((size_t)b*CCH + head*HD)*NP + q0 + wave*16;
  #pragma unroll
  for (int r=0;r<4;r++){
    int qi = quad*4 + r;
    float invl = 1.0f / l[r];
    Ob[(size_t)(l16)*NP + qi]      = __float2bfloat16(O0[r]*invl);
    Ob[(size_t)(16+l16)*NP + qi]   = __float2bfloat16(O1[r]*invl);
    Ob[(size_t)(32+l16)*NP + qi]   = __float2bfloat16(O2[r]*invl);
  }
}

// ---------------------------------------------------------------------------
extern "C" void kernel_launch(void* const* d_in, const int* in_sizes, int n_in,
                              void* d_out, int out_size, void* d_ws, size_t ws_size,
                              hipStream_t stream)
{
  // ws layout (bytes):
  //   [0]        int flag
  //   [16]       bf16 canon[153988]  (params)       ~308 KB
  //   [308096]   bf16 bufA[2*576*4096]              9.44 MB (also attn out)
  //   [9745280]  bf16 bufB[2*576*4096]              9.44 MB
  int*  flag  = (int*)d_ws;
  bf16* canon = (bf16*)((char*)d_ws + 16);
  bf16* bufA  = (bf16*)((char*)d_ws + 308096);
  bf16* bufB  = (bf16*)((char*)d_ws + 9745280);
  bf16* bufAttn = bufA;

  bf16* cw_qkv  = canon;
  bf16* cb_qkv  = canon + 110592;
  bf16* cw_dw   = canon + 111168;
  bf16* cb_dw   = canon + 116352;
  bf16* cw_proj = canon + 116928;
  bf16* cb_proj = canon + 153792;
  bf16* ctemp   = canon + 153984;

  // 0) probe input dtype
  probe_kernel<<<1, 256, 0, stream>>>((const unsigned*)d_in[0], flag);
  // 0b) convert params to canonical bf16 (both variants, flag-guarded)
  convert_params_kernel<bf16><<<602, 256, 0, stream>>>(flag, 1,
      d_in[1], d_in[2], d_in[3], d_in[4], d_in[5], d_in[6], d_in[7], canon);
  convert_params_kernel<float><<<602, 256, 0, stream>>>(flag, 0,
      d_in[1], d_in[2], d_in[3], d_in[4], d_in[5], d_in[6], d_in[7], canon);
  // 1) qkv 1x1 conv
  conv1x1_kernel<bf16,bf16><<<dim3(16,18,2), 256, 0, stream>>>(flag, 1,
      (const bf16*)d_in[0], cw_qkv, cb_qkv, bufA, C3);
  conv1x1_kernel<float,bf16><<<dim3(16,18,2), 256, 0, stream>>>(flag, 0,
      (const float*)d_in[0], cw_qkv, cb_qkv, bufA, C3);
  // 2) 3x3 depthwise + bias
  dwconv_kernel<<<dim3((BB*C3*NP)/256), 256, 0, stream>>>(bufA, cw_dw, cb_dw, bufB);
  // 3) l2norm q,k in place
  l2norm_kernel<<<dim3(256), 256, 0, stream>>>(bufB);
  // 4) flash attention -> bufAttn (aliases bufA; bufA dead after dwconv)
  flash_kernel<<<dim3(8,64), 256, 0, stream>>>(bufB, ctemp, bufAttn);
  // 5) output projection, output dtype follows probed input dtype
  conv1x1_kernel<bf16,bf16><<<dim3(16,6,2), 256, 0, stream>>>(flag, 1,
      bufAttn, cw_proj, cb_proj, (bf16*)d_out, CCH);
  conv1x1_kernel<bf16,float><<<dim3(16,6,2), 256, 0, stream>>>(flag, 0,
      bufAttn, cw_proj, cb_proj, (float*)d_out, CCH);
}

// Round 4
// 444.206 us; speedup vs baseline: 1.2904x; 1.2904x over previous
//
#include <hip/hip_runtime.h>
#include <hip/hip_bf16.h>

// MDTA: qkv 1x1 conv -> 3x3 depthwise -> l2norm(q,k) (+K^T materialize) ->
// flash attention (MFMA bf16, double-buffered, 1 barrier/iter) -> 1x1 proj.
// Input/output dtype probed at runtime (fp32 vs bf16); intermediates bf16.

#define BB 2
#define CCH 192
#define C3 576
#define NH 4
#define HD 48
#define NP 4096

typedef __hip_bfloat16 bf16;
typedef __attribute__((ext_vector_type(8))) short bf16x8;
typedef __attribute__((ext_vector_type(4))) float f32x4;

union I4B8 { int4 i; bf16x8 v; };

__device__ inline float bf2f(bf16 v){ return __bfloat162float(v); }
__device__ inline unsigned short bfbits(bf16 v){ return __builtin_bit_cast(unsigned short, v); }
__device__ inline unsigned short f2bfbits(float f){ return __builtin_bit_cast(unsigned short, __float2bfloat16(f)); }
__device__ inline float2 unpack2(unsigned u){
  float2 r; r.x = __uint_as_float(u << 16); r.y = __uint_as_float(u & 0xffff0000u); return r;
}

// ---------------------------------------------------------------------------
// Probe input dtype: bf16 data -> low short of each dword has sane exponent.
// ---------------------------------------------------------------------------
__global__ void probe_kernel(const unsigned* __restrict__ x, int* __restrict__ flag)
{
  int t = threadIdx.x;
  unsigned u = x[t];
  int e = (u >> 7) & 0xff;
  int sane = (e >= 100 && e <= 140) || ((u & 0x7fffu) == 0u);
  __shared__ int cnt;
  if (t == 0) cnt = 0;
  __syncthreads();
  if (sane) atomicAdd(&cnt, 1);
  __syncthreads();
  if (t == 0) *flag = (cnt >= 192) ? 1 : 0;
}

// ---------------------------------------------------------------------------
// Convert params to canonical bf16 (single kernel, runtime dtype branch).
// ---------------------------------------------------------------------------
#define NCANON 153988
__global__ __launch_bounds__(256) void convert_params_kernel(
    const int* __restrict__ flag,
    const void* w_qkv, const void* b_qkv, const void* w_dw, const void* b_dw,
    const void* w_proj, const void* b_proj, const void* temp,
    bf16* __restrict__ canon)
{
  const bool isbf = (*flag != 0);
  int i = blockIdx.x*256 + threadIdx.x;
  if (i >= NCANON) return;
  const void* src; int off;
  if      (i < 110592){ src = w_qkv;  off = i; }
  else if (i < 111168){ src = b_qkv;  off = i - 110592; }
  else if (i < 116352){ src = w_dw;   off = i - 111168; }
  else if (i < 116928){ src = b_dw;   off = i - 116352; }
  else if (i < 153792){ src = w_proj; off = i - 116928; }
  else if (i < 153984){ src = b_proj; off = i - 153792; }
  else                { src = temp;   off = i - 153984; }
  float v = isbf ? bf2f(((const bf16*)src)[off]) : ((const float*)src)[off];
  canon[i] = __float2bfloat16(v);
}

// ---------------------------------------------------------------------------
// 1x1 conv as GEMM, runtime dtype branches (xdyn: X follows input dtype;
// ydyn: Y follows input dtype). Block 32 o x 256 p, micro-tile 4o x 8p.
// ---------------------------------------------------------------------------
__global__ __launch_bounds__(256) void conv1x1_kernel(
    const int* __restrict__ flag, int xdyn, int ydyn,
    const void* __restrict__ Xv, const bf16* __restrict__ Wt,
    const bf16* __restrict__ bias, void* __restrict__ Yv, int OC)
{
  const bool isbf = (*flag != 0);
  const bool xf32 = xdyn && !isbf;
  const bool yf32 = ydyn && !isbf;
  __shared__ unsigned Xs[16][256];
  __shared__ unsigned Ws[16][32];
  const int tid = threadIdx.x;
  const int pl = tid & 31, og = tid >> 5;
  const int p0 = blockIdx.x * 256;
  const int o0 = blockIdx.y * 32;
  const size_t xoff = (size_t)blockIdx.z * CCH * NP;
  const size_t yoff = (size_t)blockIdx.z * OC * NP;

  float acc[4][8];
  for (int r=0;r<4;r++){ float bv = bf2f(bias[o0+og*4+r]); for (int j=0;j<8;j++) acc[r][j]=bv; }

  for (int kc=0; kc<6; kc++){
    __syncthreads();
    for (int i=tid; i<16*256; i+=256){
      int cc=i>>8, p=i&255, c=kc*32+cc*2;
      size_t i0 = xoff + (size_t)c*NP + p0+p, i1 = i0 + NP;
      unsigned lo, hi;
      if (xf32){ lo = f2bfbits(((const float*)Xv)[i0]); hi = f2bfbits(((const float*)Xv)[i1]); }
      else     { lo = bfbits(((const bf16*)Xv)[i0]);    hi = bfbits(((const bf16*)Xv)[i1]); }
      Xs[cc][p] = lo | (hi<<16);
    }
    for (int i=tid; i<16*32; i+=256){
      int cc=i>>5, o=i&31;
      const bf16* wp = Wt + (size_t)(o0+o)*CCH + kc*32 + cc*2;
      Ws[cc][o] = (unsigned)bfbits(wp[0]) | ((unsigned)bfbits(wp[1])<<16);
    }
    __syncthreads();
    #pragma unroll
    for (int cc=0; cc<16; cc++){
      float2 wv[4];
      #pragma unroll
      for (int r=0;r<4;r++) wv[r] = unpack2(Ws[cc][og*4+r]);
      #pragma unroll
      for (int j=0;j<8;j++){
        float2 xv = unpack2(Xs[cc][pl+32*j]);
        #pragma unroll
        for (int r=0;r<4;r++) acc[r][j] += wv[r].x*xv.x + wv[r].y*xv.y;
      }
    }
  }
  for (int r=0;r<4;r++)
    for (int j=0;j<8;j++){
      size_t o = yoff + (size_t)(o0+og*4+r)*NP + p0 + pl + 32*j;
      if (yf32) ((float*)Yv)[o] = acc[r][j];
      else      ((bf16*)Yv)[o] = __float2bfloat16(acc[r][j]);
    }
}

// ---------------------------------------------------------------------------
// 3x3 depthwise conv, padding 1, bf16 in/out, fp32 accumulate.
// ---------------------------------------------------------------------------
__global__ __launch_bounds__(256) void dwconv_kernel(
    const bf16* __restrict__ in, const bf16* __restrict__ w,
    const bf16* __restrict__ bias, bf16* __restrict__ out)
{
  int idx = blockIdx.x*256 + threadIdx.x;
  int pos = idx & 4095; int bc = idx >> 12; int ch = bc % C3;
  int y = pos >> 6, x = pos & 63;
  const bf16* ip = in + (size_t)bc * NP;
  float s = bf2f(bias[ch]);
  #pragma unroll
  for (int ky=0;ky<3;ky++){
    int yy = y + ky - 1; if (yy < 0 || yy > 63) continue;
    #pragma unroll
    for (int kx=0;kx<3;kx++){
      int xx = x + kx - 1; if (xx < 0 || xx > 63) continue;
      s += bf2f(w[ch*9 + ky*3 + kx]) * bf2f(ip[yy*64 + xx]);
    }
  }
  out[idx] = __float2bfloat16(s);
}

// ---------------------------------------------------------------------------
// L2 normalize q (in place) and k (-> materialized K^T [bh][n][64] bf16,
// zero-padded d 48..63, 16B-unit XOR swizzle by n&7 for conflict-free MFMA
// fragment reads).
// ---------------------------------------------------------------------------
__global__ __launch_bounds__(256) void l2norm_t_kernel(
    bf16* __restrict__ buf, short* __restrict__ KT)
{
  int idx = blockIdx.x*256 + threadIdx.x;   // 65536 total
  int n = idx & 4095; int t = idx >> 12;
  int head = t & 3; int qk = (t>>2)&1; int b = t>>3;
  bf16* p = buf + ((size_t)b*C3 + qk*CCH + head*HD)*NP + n;
  float v[HD];
  float ss = 0.f;
  #pragma unroll
  for (int d=0; d<HD; d++){ v[d] = bf2f(p[(size_t)d*NP]); ss += v[d]*v[d]; }
  float inv = 1.0f / fmaxf(sqrtf(ss), 1e-12f);
  if (qk == 0){
    #pragma unroll
    for (int d=0; d<HD; d++) p[(size_t)d*NP] = __float2bfloat16(v[d]*inv);
  } else {
    short* row = KT + ((size_t)(b*NH+head)*NP + n)*64;
    int sw = n & 7;
    #pragma unroll
    for (int u=0; u<8; u++){
      int4 w = {0,0,0,0};
      if (u < 6){
        int d0 = u*8;
        w.x = (unsigned)f2bfbits(v[d0+0]*inv) | ((unsigned)f2bfbits(v[d0+1]*inv)<<16);
        w.y = (unsigned)f2bfbits(v[d0+2]*inv) | ((unsigned)f2bfbits(v[d0+3]*inv)<<16);
        w.z = (unsigned)f2bfbits(v[d0+4]*inv) | ((unsigned)f2bfbits(v[d0+5]*inv)<<16);
        w.w = (unsigned)f2bfbits(v[d0+6]*inv) | ((unsigned)f2bfbits(v[d0+7]*inv)<<16);
      }
      *(int4*)&row[(u^sw)*8] = w;
    }
  }
}

// ---------------------------------------------------------------------------
// Flash attention, mfma_f32_16x16x32_bf16, K chunk 128, double-buffered K/V
// staging, ONE barrier per iteration. P LDS round-trip is wave-private
// (no barrier). Q fragments loaded global->reg once.
// Layouts: A[m=lane&15][k=quad*8+j], B[k=quad*8+j][n=lane&15],
// C/D col=lane&15 row=quad*4+reg.
// ---------------------------------------------------------------------------
__global__ __launch_bounds__(256) void flash_kernel(
    const bf16* __restrict__ qkv,      // bufB [b][c3][n]
    const short* __restrict__ KT,      // [bh][n][64] swizzled bf16 bits
    const bf16* __restrict__ temp,
    bf16* __restrict__ outp)           // [b][192][n]
{
  __shared__ __align__(16) short Ks[2][128*64];   // 32 KB
  __shared__ __align__(16) short Vs[2][48*136];   // 26112 B
  __shared__ __align__(16) short Ps[4][16*136];   // 17408 B

  const int bh = blockIdx.x, b = bh>>2, head = bh&3;
  const int q0 = blockIdx.y * 64;
  const int tid = threadIdx.x, wave = tid>>6, lane = tid&63;
  const int l16 = lane&15, quad = lane>>4;

  const unsigned short* Qp = (const unsigned short*)(qkv + ((size_t)b*C3 + head*HD)*NP)
                             + q0 + wave*16 + l16;
  const short* Vp = (const short*)(qkv + ((size_t)b*C3 + 2*CCH + head*HD)*NP);
  const short* KTs = KT + (size_t)bh*NP*64;
  const float sc = bf2f(temp[head]) * 1.44269504f;

  // Q fragments direct from global (A-layout: m=l16 -> q-row, kk=quad*8+j)
  I4B8 A0, A1;
  {
    unsigned q0b[8];
    #pragma unroll
    for (int j=0;j<8;j++) q0b[j] = Qp[(size_t)(quad*8+j)*NP];
    A0.i.x = q0b[0] | (q0b[1]<<16); A0.i.y = q0b[2] | (q0b[3]<<16);
    A0.i.z = q0b[4] | (q0b[5]<<16); A0.i.w = q0b[6] | (q0b[7]<<16);
    if (quad < 2){
      unsigned q1b[8];
      #pragma unroll
      for (int j=0;j<8;j++) q1b[j] = Qp[(size_t)(32+quad*8+j)*NP];
      A1.i.x = q1b[0] | (q1b[1]<<16); A1.i.y = q1b[2] | (q1b[3]<<16);
      A1.i.z = q1b[4] | (q1b[5]<<16); A1.i.w = q1b[6] | (q1b[7]<<16);
    } else {
      A1.i.x = 0; A1.i.y = 0; A1.i.z = 0; A1.i.w = 0;
    }
  }

  f32x4 O0 = {0,0,0,0}, O1 = {0,0,0,0}, O2 = {0,0,0,0};
  float m[4], l[4];
  #pragma unroll
  for (int r=0;r<4;r++){ m[r] = -INFINITY; l[r] = 0.f; }
  short* Pw = Ps[wave];
  const int sw = l16 & 7;

  // ---- staging helper (inlined twice) ----
  #define STAGE(CHUNK, BUFI) do {                                            \
    const int k0_ = (CHUNK) << 7;                                            \
    const int4* gk_ = (const int4*)(KTs + (size_t)k0_*64);                   \
    int4* lk_ = (int4*)&Ks[(BUFI)][0];                                       \
    _Pragma("unroll")                                                        \
    for (int s_=0; s_<4; s_++) lk_[tid + 256*s_] = gk_[tid + 256*s_];        \
    _Pragma("unroll")                                                        \
    for (int s_=0; s_<3; s_++){                                              \
      int i_ = tid + 256*s_; int d_ = i_>>4, kb_ = i_&15;                    \
      *(int4*)&Vs[(BUFI)][d_*136 + kb_*8] =                                  \
        *(const int4*)(Vp + (size_t)d_*NP + k0_ + kb_*8);                    \
    }                                                                        \
  } while(0)

  STAGE(0, 0);
  __syncthreads();

  for (int t=0; t<32; ++t){
    const int cur = t & 1;
    if (t < 31) STAGE(t+1, cur^1);

    const short* Kb = &Ks[cur][0];
    const short* Vb = &Vs[cur][0];

    // S = Q K^T : 8 col-tiles of 16 keys
    f32x4 S[8];
    #pragma unroll
    for (int ct=0; ct<8; ++ct){
      const int row = (ct*16 + l16)*64;
      I4B8 B0, B1;
      B0.i = *(const int4*)&Kb[row + ((quad^sw)*8)];
      B1.i = *(const int4*)&Kb[row + (((4+quad)^sw)*8)];
      f32x4 z = {0,0,0,0};
      z = __builtin_amdgcn_mfma_f32_16x16x32_bf16(A0.v, B0.v, z, 0,0,0);
      z = __builtin_amdgcn_mfma_f32_16x16x32_bf16(A1.v, B1.v, z, 0,0,0);
      S[ct] = z;
    }

    // online softmax (4 q-rows per lane; row spread over 16 lanes x 8 tiles)
    #pragma unroll
    for (int r=0;r<4;r++){
      float a[8];
      #pragma unroll
      for (int ct=0;ct<8;ct++) a[ct] = S[ct][r]*sc;
      float mx = a[0];
      #pragma unroll
      for (int ct=1;ct<8;ct++) mx = fmaxf(mx, a[ct]);
      mx = fmaxf(mx, __shfl_xor(mx,1));
      mx = fmaxf(mx, __shfl_xor(mx,2));
      mx = fmaxf(mx, __shfl_xor(mx,4));
      mx = fmaxf(mx, __shfl_xor(mx,8));
      float mn = fmaxf(m[r], mx);
      float al = exp2f(m[r]-mn);
      float rs = 0.f;
      #pragma unroll
      for (int ct=0;ct<8;ct++){
        float p = exp2f(a[ct]-mn);
        rs += p;
        Pw[(quad*4+r)*136 + ct*16 + l16] = (short)f2bfbits(p);
      }
      rs += __shfl_xor(rs,1);
      rs += __shfl_xor(rs,2);
      rs += __shfl_xor(rs,4);
      rs += __shfl_xor(rs,8);
      l[r] = l[r]*al + rs; m[r] = mn;
      O0[r]*=al; O1[r]*=al; O2[r]*=al;
    }

    // O += P V  (P wave-private in LDS: no barrier needed, lgkmcnt orders)
    #pragma unroll
    for (int c=0;c<4;c++){
      I4B8 AP, BV0, BV1, BV2;
      AP.i  = *(const int4*)&Pw[l16*136 + c*32 + quad*8];
      BV0.i = *(const int4*)&Vb[(l16     )*136 + c*32 + quad*8];
      BV1.i = *(const int4*)&Vb[(16+l16)*136 + c*32 + quad*8];
      BV2.i = *(const int4*)&Vb[(32+l16)*136 + c*32 + quad*8];
      O0 = __builtin_amdgcn_mfma_f32_16x16x32_bf16(AP.v, BV0.v, O0, 0,0,0);
      O1 = __builtin_amdgcn_mfma_f32_16x16x32_bf16(AP.v, BV1.v, O1, 0,0,0);
      O2 = __builtin_amdgcn_mfma_f32_16x16x32_bf16(AP.v, BV2.v, O2, 0,0,0);
    }
    __syncthreads();   // staged buf ready for t+1; cur free for restage
  }

  bf16* Ob = outp + ((size_t)b*CCH + head*HD)*NP + q0 + wave*16;
  #pragma unroll
  for (int r=0;r<4;r++){
    int qi = quad*4 + r;
    float invl = 1.0f / l[r];
    Ob[(size_t)(l16)*NP + qi]      = __float2bfloat16(O0[r]*invl);
    Ob[(size_t)(16+l16)*NP + qi]   = __float2bfloat16(O1[r]*invl);
    Ob[(size_t)(32+l16)*NP + qi]   = __float2bfloat16(O2[r]*invl);
  }
}

// ---------------------------------------------------------------------------
extern "C" void kernel_launch(void* const* d_in, const int* in_sizes, int n_in,
                              void* d_out, int out_size, void* d_ws, size_t ws_size,
                              hipStream_t stream)
{
  // ws layout (bytes) — same proven footprint as R3 (19.2 MB):
  //   [0]        int flag
  //   [16]       bf16 canon[153988]
  //   [308096]   bf16 bufA[2*576*4096]   (attn out in first 1.57M el,
  //                                       K^T at el offset 1572864: 2.09M el)
  //   [9745280]  bf16 bufB[2*576*4096]
  int*  flag  = (int*)d_ws;
  bf16* canon = (bf16*)((char*)d_ws + 16);
  bf16* bufA  = (bf16*)((char*)d_ws + 308096);
  bf16* bufB  = (bf16*)((char*)d_ws + 9745280);
  bf16* bufAttn = bufA;                         // [2][192][4096]
  short* KT = (short*)(bufA + 1572864);         // [8][4096][64]

  bf16* cw_qkv  = canon;
  bf16* cb_qkv  = canon + 110592;
  bf16* cw_dw   = canon + 111168;
  bf16* cb_dw   = canon + 116352;
  bf16* cw_proj = canon + 116928;
  bf16* cb_proj = canon + 153792;
  bf16* ctemp   = canon + 153984;

  probe_kernel<<<1, 256, 0, stream>>>((const unsigned*)d_in[0], flag);
  convert_params_kernel<<<602, 256, 0, stream>>>(flag,
      d_in[1], d_in[2], d_in[3], d_in[4], d_in[5], d_in[6], d_in[7], canon);
  // 1) qkv 1x1 conv (X dtype dynamic)
  conv1x1_kernel<<<dim3(16,18,2), 256, 0, stream>>>(flag, 1, 0,
      d_in[0], cw_qkv, cb_qkv, bufA, C3);
  // 2) 3x3 depthwise
  dwconv_kernel<<<dim3((BB*C3*NP)/256), 256, 0, stream>>>(bufA, cw_dw, cb_dw, bufB);
  // 3) l2norm q in place + K^T materialize (swizzled, zero-padded)
  l2norm_t_kernel<<<dim3(256), 256, 0, stream>>>(bufB, KT);
  // 4) flash attention -> bufAttn
  flash_kernel<<<dim3(8,64), 256, 0, stream>>>(bufB, KT, ctemp, bufAttn);
  // 5) output projection (Y dtype dynamic)
  conv1x1_kernel<<<dim3(16,6,2), 256, 0, stream>>>(flag, 0, 1,
      bufAttn, cw_proj, cb_proj, d_out, CCH);
}

// Round 5
// 306.114 us; speedup vs baseline: 1.8725x; 1.4511x over previous
//
#include <hip/hip_runtime.h>
#include <hip/hip_bf16.h>

// MDTA: transpose X -> qkv 1x1 conv (MFMA GEMM) -> 3x3 depthwise (LDS) ->
// l2norm(q)+K^T materialize -> flash attention (MFMA, dbuf, 1 barrier/iter,
// loads-compute-store pipelining) -> 1x1 proj (MFMA GEMM).
// Input/output dtype probed at runtime; intermediates bf16 in d_ws.

#define BB 2
#define CCH 192
#define C3 576
#define NH 4
#define HD 48
#define NP 4096

typedef __hip_bfloat16 bf16;
typedef __attribute__((ext_vector_type(8))) short bf16x8;
typedef __attribute__((ext_vector_type(4))) float f32x4;

union I4B8 { int4 i; bf16x8 v; };

__device__ inline float bf2f(bf16 v){ return __bfloat162float(v); }
__device__ inline unsigned short bfbits(bf16 v){ return __builtin_bit_cast(unsigned short, v); }
__device__ inline unsigned short f2bfbits(float f){ return __builtin_bit_cast(unsigned short, __float2bfloat16(f)); }
__device__ inline float bfb2f(short s){ return __uint_as_float(((unsigned)(unsigned short)s)<<16); }

// ---------------------------------------------------------------------------
// Probe input dtype: bf16 data -> low short of each dword has sane exponent.
// ---------------------------------------------------------------------------
__global__ void probe_kernel(const unsigned* __restrict__ x, int* __restrict__ flag)
{
  int t = threadIdx.x;
  unsigned u = x[t];
  int e = (u >> 7) & 0xff;
  int sane = (e >= 100 && e <= 140) || ((u & 0x7fffu) == 0u);
  __shared__ int cnt;
  if (t == 0) cnt = 0;
  __syncthreads();
  if (sane) atomicAdd(&cnt, 1);
  __syncthreads();
  if (t == 0) *flag = (cnt >= 192) ? 1 : 0;
}

// ---------------------------------------------------------------------------
// Convert params to canonical bf16.
// ---------------------------------------------------------------------------
#define NCANON 153988
__global__ __launch_bounds__(256) void convert_params_kernel(
    const int* __restrict__ flag,
    const void* w_qkv, const void* b_qkv, const void* w_dw, const void* b_dw,
    const void* w_proj, const void* b_proj, const void* temp,
    bf16* __restrict__ canon)
{
  const bool isbf = (*flag != 0);
  int i = blockIdx.x*256 + threadIdx.x;
  if (i >= NCANON) return;
  const void* src; int off;
  if      (i < 110592){ src = w_qkv;  off = i; }
  else if (i < 111168){ src = b_qkv;  off = i - 110592; }
  else if (i < 116352){ src = w_dw;   off = i - 111168; }
  else if (i < 116928){ src = b_dw;   off = i - 116352; }
  else if (i < 153792){ src = w_proj; off = i - 116928; }
  else if (i < 153984){ src = b_proj; off = i - 153792; }
  else                { src = temp;   off = i - 153984; }
  float v = isbf ? bf2f(((const bf16*)src)[off]) : ((const float*)src)[off];
  canon[i] = __float2bfloat16(v);
}

// ---------------------------------------------------------------------------
// Transpose X [b][192][4096] (dyn dtype) -> XT [b][4096][192] bf16 bits.
// 64c x 64p LDS tiles, pad 66 (2-way bank alias = free).
// ---------------------------------------------------------------------------
__global__ __launch_bounds__(256) void transpose_x_kernel(
    const int* __restrict__ flag, const void* __restrict__ Xv,
    short* __restrict__ XT)
{
  const bool isbf = (*flag != 0);
  __shared__ short T[64][66];
  const int c0 = blockIdx.x*64, p0 = blockIdx.y*64, b = blockIdx.z;
  const size_t xbase = (size_t)b*CCH*NP;
  #pragma unroll
  for (int s=0;s<16;s++){
    int i = threadIdx.x + s*256;
    int cc = i>>6, pp = i&63;
    size_t g = xbase + (size_t)(c0+cc)*NP + p0+pp;
    float v = isbf ? bf2f(((const bf16*)Xv)[g]) : ((const float*)Xv)[g];
    T[cc][pp] = (short)f2bfbits(v);
  }
  __syncthreads();
  #pragma unroll
  for (int s=0;s<16;s++){
    int i = threadIdx.x + s*256;
    int pl = i>>6, cl = i&63;
    XT[((size_t)b*NP + p0+pl)*CCH + c0+cl] = T[cl][pl];
  }
}

// ---------------------------------------------------------------------------
// 1x1 conv as MFMA GEMM.  Y[b][o][p] = bias[o] + sum_c W[o][c]*X[c][p].
// A = W (m=o, k=c, b128 from L2), B = XT tile (n=p, k=c, LDS dbuf).
// Block 64o x 128p, wave = 32p x 64o (4m x 2n tiles). K=192 in 6 chunks.
// Layouts (flash-verified): A[m=l16][k=quad*8+j], B[n=l16][k=quad*8+j],
// D col(n)=l16, row(m)=quad*4+reg.
// ---------------------------------------------------------------------------
__global__ __launch_bounds__(256) void conv1x1_mfma_kernel(
    const int* __restrict__ flag, int ydyn,
    const short* __restrict__ XT,      // [b][4096][192] bf16 bits
    const bf16* __restrict__ Wt,       // [OC][192]
    const bf16* __restrict__ bias,
    void* __restrict__ Yv, int OC)
{
  const bool yf32 = ydyn && (*flag == 0);
  __shared__ __align__(16) short Bs[2][128*32];   // 2 x 8 KB
  const int tid = threadIdx.x, wave = tid>>6, lane = tid&63;
  const int l16 = lane&15, quad = lane>>4;
  const int o0 = blockIdx.x*64, p0 = blockIdx.y*128, b = blockIdx.z;
  const short* XTb = XT + ((size_t)b*NP + p0)*CCH;
  const short* Wb  = (const short*)Wt;

  f32x4 acc[4][2];
  #pragma unroll
  for (int mt=0;mt<4;mt++){
    #pragma unroll
    for (int r=0;r<4;r++){
      float bv = bf2f(bias[o0+mt*16+quad*4+r]);
      acc[mt][0][r]=bv; acc[mt][1][r]=bv;
    }
  }

  int4 sreg[2];
  I4B8 Afr[2][4];
  #define CLOAD(kc) { _Pragma("unroll") for (int s_=0;s_<2;s_++){ int i_=tid+256*s_; \
      sreg[s_] = *(const int4*)&XTb[(size_t)(i_>>2)*CCH + (kc)*32 + (i_&3)*8]; } }
  #define CSTORE(buf) { _Pragma("unroll") for (int s_=0;s_<2;s_++){ int i_=tid+256*s_; \
      *(int4*)&Bs[buf][(i_>>2)*32 + (i_&3)*8] = sreg[s_]; } }
  #define ALOAD(kc, buf) { _Pragma("unroll") for (int mt_=0;mt_<4;mt_++){ \
      Afr[buf][mt_].i = *(const int4*)&Wb[(size_t)(o0+mt_*16+l16)*CCH + (kc)*32 + quad*8]; } }

  CLOAD(0); CSTORE(0); ALOAD(0,0);
  __syncthreads();

  #pragma unroll
  for (int kc=0; kc<6; kc++){
    const int cur = kc&1;
    if (kc<5){ CLOAD(kc+1); ALOAD(kc+1, cur^1); }
    I4B8 Bf0, Bf1;
    Bf0.i = *(const int4*)&Bs[cur][(wave*32 + l16)*32 + quad*8];
    Bf1.i = *(const int4*)&Bs[cur][(wave*32 + 16 + l16)*32 + quad*8];
    #pragma unroll
    for (int mt=0;mt<4;mt++){
      acc[mt][0] = __builtin_amdgcn_mfma_f32_16x16x32_bf16(Afr[cur][mt].v, Bf0.v, acc[mt][0], 0,0,0);
      acc[mt][1] = __builtin_amdgcn_mfma_f32_16x16x32_bf16(Afr[cur][mt].v, Bf1.v, acc[mt][1], 0,0,0);
    }
    if (kc<5) CSTORE(cur^1);
    __syncthreads();
  }
  #undef CLOAD
  #undef CSTORE
  #undef ALOAD

  #pragma unroll
  for (int mt=0;mt<4;mt++)
    #pragma unroll
    for (int nt=0;nt<2;nt++)
      #pragma unroll
      for (int r=0;r<4;r++){
        int o = o0 + mt*16 + quad*4 + r;
        int p = p0 + wave*32 + nt*16 + l16;
        size_t off = ((size_t)b*OC + o)*NP + p;
        if (yf32) ((float*)Yv)[off] = acc[mt][nt][r];
        else      ((bf16*)Yv)[off]  = __float2bfloat16(acc[mt][nt][r]);
      }
}

// ---------------------------------------------------------------------------
// 3x3 depthwise conv, padding 1. One block per (b,ch) image; image in LDS
// via b128; 16 px/thread; b128 stores.
// ---------------------------------------------------------------------------
__global__ __launch_bounds__(256) void dwconv_kernel(
    const bf16* __restrict__ in, const bf16* __restrict__ w,
    const bf16* __restrict__ bias, bf16* __restrict__ out)
{
  __shared__ __align__(16) short img[4096];
  const int bc = blockIdx.x; const int ch = bc % C3;
  const int tid = threadIdx.x;
  const int4* g4 = (const int4*)(in + (size_t)bc*NP);
  int4* s4 = (int4*)img;
  s4[tid] = g4[tid];
  s4[tid+256] = g4[tid+256];
  float wv[9];
  #pragma unroll
  for (int j=0;j<9;j++) wv[j] = bf2f(w[ch*9+j]);
  const float bv = bf2f(bias[ch]);
  __syncthreads();

  const int y = tid>>2, x0 = (tid&3)*16;
  unsigned outw[8];
  #pragma unroll
  for (int j=0;j<16;j++){
    int x = x0+j;
    float s = bv;
    #pragma unroll
    for (int ky=0;ky<3;ky++){
      int yy = y+ky-1; if (yy<0||yy>63) continue;
      const short* rp = &img[yy<<6];
      #pragma unroll
      for (int kx=0;kx<3;kx++){
        int xx = x+kx-1; if (xx<0||xx>63) continue;
        s += wv[ky*3+kx]*bfb2f(rp[xx]);
      }
    }
    unsigned hb = f2bfbits(s);
    if (j&1) outw[j>>1] |= hb<<16; else outw[j>>1] = hb;
  }
  int4* op = (int4*)((short*)out + (size_t)bc*NP + (y<<6) + x0);
  op[0] = *(int4*)&outw[0];
  op[1] = *(int4*)&outw[4];
}

// ---------------------------------------------------------------------------
// L2 normalize q (in place) and k (-> K^T [bh][n][64], zero-padded d 48..63,
// 16B-unit XOR swizzle by n&7).
// ---------------------------------------------------------------------------
__global__ __launch_bounds__(256) void l2norm_t_kernel(
    bf16* __restrict__ buf, short* __restrict__ KT)
{
  int idx = blockIdx.x*256 + threadIdx.x;   // 65536 total
  int n = idx & 4095; int t = idx >> 12;
  int head = t & 3; int qk = (t>>2)&1; int b = t>>3;
  bf16* p = buf + ((size_t)b*C3 + qk*CCH + head*HD)*NP + n;
  float v[HD];
  float ss = 0.f;
  #pragma unroll
  for (int d=0; d<HD; d++){ v[d] = bf2f(p[(size_t)d*NP]); ss += v[d]*v[d]; }
  float inv = 1.0f / fmaxf(sqrtf(ss), 1e-12f);
  if (qk == 0){
    #pragma unroll
    for (int d=0; d<HD; d++) p[(size_t)d*NP] = __float2bfloat16(v[d]*inv);
  } else {
    short* row = KT + ((size_t)(b*NH+head)*NP + n)*64;
    int sw = n & 7;
    #pragma unroll
    for (int u=0; u<8; u++){
      int4 w = {0,0,0,0};
      if (u < 6){
        int d0 = u*8;
        w.x = (unsigned)f2bfbits(v[d0+0]*inv) | ((unsigned)f2bfbits(v[d0+1]*inv)<<16);
        w.y = (unsigned)f2bfbits(v[d0+2]*inv) | ((unsigned)f2bfbits(v[d0+3]*inv)<<16);
        w.z = (unsigned)f2bfbits(v[d0+4]*inv) | ((unsigned)f2bfbits(v[d0+5]*inv)<<16);
        w.w = (unsigned)f2bfbits(v[d0+6]*inv) | ((unsigned)f2bfbits(v[d0+7]*inv)<<16);
      }
      *(int4*)&row[(u^sw)*8] = w;
    }
  }
}

// ---------------------------------------------------------------------------
// Flash attention, mfma_f32_16x16x32_bf16, K chunk 128, dbuf, 1 barrier/iter,
// loads -> compute -> ds_write ordering (vmcnt drain after the MFMAs).
// Writes O^T [b][n][192] bf16 for the MFMA proj conv.
// ---------------------------------------------------------------------------
__global__ __launch_bounds__(256) void flash_kernel(
    const bf16* __restrict__ qkv,      // bufB [b][c3][n]
    const short* __restrict__ KT,      // [bh][n][64] swizzled bf16 bits
    const bf16* __restrict__ temp,
    short* __restrict__ OT)            // [b][4096][192] bf16 bits
{
  __shared__ __align__(16) short Ks[2][128*64];
  __shared__ __align__(16) short Vs[2][48*136];
  __shared__ __align__(16) short Ps[4][16*136];

  const int bh = blockIdx.x, b = bh>>2, head = bh&3;
  const int q0 = blockIdx.y * 64;
  const int tid = threadIdx.x, wave = tid>>6, lane = tid&63;
  const int l16 = lane&15, quad = lane>>4;

  const unsigned short* Qp = (const unsigned short*)(qkv + ((size_t)b*C3 + head*HD)*NP)
                             + q0 + wave*16 + l16;
  const short* Vp = (const short*)(qkv + ((size_t)b*C3 + 2*CCH + head*HD)*NP);
  const short* KTs = KT + (size_t)bh*NP*64;
  const float sc = bf2f(temp[head]) * 1.44269504f;

  I4B8 A0, A1;
  {
    unsigned q0b[8];
    #pragma unroll
    for (int j=0;j<8;j++) q0b[j] = Qp[(size_t)(quad*8+j)*NP];
    A0.i.x = q0b[0] | (q0b[1]<<16); A0.i.y = q0b[2] | (q0b[3]<<16);
    A0.i.z = q0b[4] | (q0b[5]<<16); A0.i.w = q0b[6] | (q0b[7]<<16);
    if (quad < 2){
      unsigned q1b[8];
      #pragma unroll
      for (int j=0;j<8;j++) q1b[j] = Qp[(size_t)(32+quad*8+j)*NP];
      A1.i.x = q1b[0] | (q1b[1]<<16); A1.i.y = q1b[2] | (q1b[3]<<16);
      A1.i.z = q1b[4] | (q1b[5]<<16); A1.i.w = q1b[6] | (q1b[7]<<16);
    } else {
      A1.i.x = 0; A1.i.y = 0; A1.i.z = 0; A1.i.w = 0;
    }
  }

  f32x4 O0 = {0,0,0,0}, O1 = {0,0,0,0}, O2 = {0,0,0,0};
  float m[4], l[4];
  #pragma unroll
  for (int r=0;r<4;r++){ m[r] = -INFINITY; l[r] = 0.f; }
  short* Pw = Ps[wave];
  const int sw = l16 & 7;

  int4 kreg[4], vreg[3];
  #define KLOAD(CHUNK) { const int k0_=(CHUNK)<<7; \
    const int4* gk_ = (const int4*)(KTs + (size_t)k0_*64); \
    _Pragma("unroll") for (int s_=0;s_<4;s_++) kreg[s_] = gk_[tid + 256*s_]; \
    _Pragma("unroll") for (int s_=0;s_<3;s_++){ int i_=tid+256*s_; \
      vreg[s_] = *(const int4*)(Vp + (size_t)(i_>>4)*NP + k0_ + (i_&15)*8); } }
  #define KSTORE(BUFI) { int4* lk_ = (int4*)&Ks[BUFI][0]; \
    _Pragma("unroll") for (int s_=0;s_<4;s_++) lk_[tid+256*s_] = kreg[s_]; \
    _Pragma("unroll") for (int s_=0;s_<3;s_++){ int i_=tid+256*s_; \
      *(int4*)&Vs[BUFI][(i_>>4)*136 + (i_&15)*8] = vreg[s_]; } }

  KLOAD(0); KSTORE(0);
  __syncthreads();

  for (int t=0; t<32; ++t){
    const int cur = t & 1;
    if (t < 31) KLOAD(t+1);

    const short* Kb = &Ks[cur][0];
    const short* Vb = &Vs[cur][0];

    f32x4 S[8];
    #pragma unroll
    for (int ct=0; ct<8; ++ct){
      const int row = (ct*16 + l16)*64;
      I4B8 B0, B1;
      B0.i = *(const int4*)&Kb[row + ((quad^sw)*8)];
      B1.i = *(const int4*)&Kb[row + (((4+quad)^sw)*8)];
      f32x4 z = {0,0,0,0};
      z = __builtin_amdgcn_mfma_f32_16x16x32_bf16(A0.v, B0.v, z, 0,0,0);
      z = __builtin_amdgcn_mfma_f32_16x16x32_bf16(A1.v, B1.v, z, 0,0,0);
      S[ct] = z;
    }

    #pragma unroll
    for (int r=0;r<4;r++){
      float a[8];
      #pragma unroll
      for (int ct=0;ct<8;ct++) a[ct] = S[ct][r]*sc;
      float mx = a[0];
      #pragma unroll
      for (int ct=1;ct<8;ct++) mx = fmaxf(mx, a[ct]);
      mx = fmaxf(mx, __shfl_xor(mx,1));
      mx = fmaxf(mx, __shfl_xor(mx,2));
      mx = fmaxf(mx, __shfl_xor(mx,4));
      mx = fmaxf(mx, __shfl_xor(mx,8));
      float mn = fmaxf(m[r], mx);
      float al = exp2f(m[r]-mn);
      float rs = 0.f;
      #pragma unroll
      for (int ct=0;ct<8;ct++){
        float p = exp2f(a[ct]-mn);
        rs += p;
        Pw[(quad*4+r)*136 + ct*16 + l16] = (short)f2bfbits(p);
      }
      rs += __shfl_xor(rs,1);
      rs += __shfl_xor(rs,2);
      rs += __shfl_xor(rs,4);
      rs += __shfl_xor(rs,8);
      l[r] = l[r]*al + rs; m[r] = mn;
      O0[r]*=al; O1[r]*=al; O2[r]*=al;
    }

    #pragma unroll
    for (int c=0;c<4;c++){
      I4B8 AP, BV0, BV1, BV2;
      AP.i  = *(const int4*)&Pw[l16*136 + c*32 + quad*8];
      BV0.i = *(const int4*)&Vb[(l16   )*136 + c*32 + quad*8];
      BV1.i = *(const int4*)&Vb[(16+l16)*136 + c*32 + quad*8];
      BV2.i = *(const int4*)&Vb[(32+l16)*136 + c*32 + quad*8];
      O0 = __builtin_amdgcn_mfma_f32_16x16x32_bf16(AP.v, BV0.v, O0, 0,0,0);
      O1 = __builtin_amdgcn_mfma_f32_16x16x32_bf16(AP.v, BV1.v, O1, 0,0,0);
      O2 = __builtin_amdgcn_mfma_f32_16x16x32_bf16(AP.v, BV2.v, O2, 0,0,0);
    }

    if (t < 31) KSTORE(cur^1);
    __syncthreads();
  }
  #undef KLOAD
  #undef KSTORE

  // O^T epilogue: row = query position, cols = head*48 + d  (32B coalesced)
  #pragma unroll
  for (int r=0;r<4;r++){
    float invl = 1.0f / l[r];
    short* row = OT + ((size_t)b*NP + q0 + wave*16 + quad*4 + r)*CCH + head*HD;
    row[l16]    = (short)f2bfbits(O0[r]*invl);
    row[16+l16] = (short)f2bfbits(O1[r]*invl);
    row[32+l16] = (short)f2bfbits(O2[r]*invl);
  }
}

// ---------------------------------------------------------------------------
extern "C" void kernel_launch(void* const* d_in, const int* in_sizes, int n_in,
                              void* d_out, int out_size, void* d_ws, size_t ws_size,
                              hipStream_t stream)
{
  // ws layout (bytes) — same 19.2 MB footprint proven in R3/R4:
  //   [0]        int flag
  //   [16]       bf16 canon[153988]
  //   [308096]   bf16 bufA[2*576*4096]  (O^T in first 1.57M el;
  //                                      K^T at el 1572864..3670016)
  //   [9745280]  bf16 bufB[2*576*4096]  (X^T borrows first 1.57M el pre-dwconv)
  int*  flag  = (int*)d_ws;
  bf16* canon = (bf16*)((char*)d_ws + 16);
  bf16* bufA  = (bf16*)((char*)d_ws + 308096);
  bf16* bufB  = (bf16*)((char*)d_ws + 9745280);
  short* XT = (short*)bufB;                     // [2][4096][192], dead after qkv conv
  short* OT = (short*)bufA;                     // [2][4096][192]
  short* KT = (short*)(bufA + 1572864);         // [8][4096][64]

  bf16* cw_qkv  = canon;
  bf16* cb_qkv  = canon + 110592;
  bf16* cw_dw   = canon + 111168;
  bf16* cb_dw   = canon + 116352;
  bf16* cw_proj = canon + 116928;
  bf16* cb_proj = canon + 153792;
  bf16* ctemp   = canon + 153984;

  probe_kernel<<<1, 256, 0, stream>>>((const unsigned*)d_in[0], flag);
  convert_params_kernel<<<602, 256, 0, stream>>>(flag,
      d_in[1], d_in[2], d_in[3], d_in[4], d_in[5], d_in[6], d_in[7], canon);
  // 0c) X -> X^T bf16
  transpose_x_kernel<<<dim3(3,64,2), 256, 0, stream>>>(flag, d_in[0], XT);
  // 1) qkv 1x1 conv (MFMA): XT, W -> bufA [2][576][4096]
  conv1x1_mfma_kernel<<<dim3(9,32,2), 256, 0, stream>>>(flag, 0,
      XT, cw_qkv, cb_qkv, bufA, C3);
  // 2) 3x3 depthwise: bufA -> bufB (overwrites XT, which is dead)
  dwconv_kernel<<<dim3(BB*C3), 256, 0, stream>>>(bufA, cw_dw, cb_dw, bufB);
  // 3) l2norm q in place + K^T materialize
  l2norm_t_kernel<<<dim3(256), 256, 0, stream>>>(bufB, KT);
  // 4) flash attention -> O^T (bufA head; KT in bufA tail, no overlap)
  flash_kernel<<<dim3(8,64), 256, 0, stream>>>(bufB, KT, ctemp, OT);
  // 5) proj 1x1 conv (MFMA): OT, W -> d_out (dtype follows input)
  conv1x1_mfma_kernel<<<dim3(3,32,2), 256, 0, stream>>>(flag, 1,
      OT, cw_proj, cb_proj, d_out, CCH);
}

// Round 6
// 205.433 us; speedup vs baseline: 2.7902x; 1.4901x over previous
//
#include <hip/hip_runtime.h>
#include <hip/hip_bf16.h>

// MDTA: transpose X -> qkv 1x1 conv (MFMA GEMM) -> 3x3 depthwise (LDS) ->
// l2norm(q)+K^T materialize -> flash attention (MFMA, dbuf, 1 barrier/iter,
// NO in-loop cross-lane ops: fixed-max softmax exploiting |q.k|<=1) ->
// 1x1 proj (MFMA GEMM).
// Input/output dtype probed at runtime; intermediates bf16 in d_ws.

#define BB 2
#define CCH 192
#define C3 576
#define NH 4
#define HD 48
#define NP 4096

typedef __hip_bfloat16 bf16;
typedef __attribute__((ext_vector_type(8))) short bf16x8;
typedef __attribute__((ext_vector_type(4))) float f32x4;

union I4B8 { int4 i; bf16x8 v; };

__device__ inline float bf2f(bf16 v){ return __bfloat162float(v); }
__device__ inline unsigned short bfbits(bf16 v){ return __builtin_bit_cast(unsigned short, v); }
__device__ inline unsigned short f2bfbits(float f){ return __builtin_bit_cast(unsigned short, __float2bfloat16(f)); }
__device__ inline float bfb2f(short s){ return __uint_as_float(((unsigned)(unsigned short)s)<<16); }

// ---------------------------------------------------------------------------
// Probe input dtype: bf16 data -> low short of each dword has sane exponent.
// ---------------------------------------------------------------------------
__global__ void probe_kernel(const unsigned* __restrict__ x, int* __restrict__ flag)
{
  int t = threadIdx.x;
  unsigned u = x[t];
  int e = (u >> 7) & 0xff;
  int sane = (e >= 100 && e <= 140) || ((u & 0x7fffu) == 0u);
  __shared__ int cnt;
  if (t == 0) cnt = 0;
  __syncthreads();
  if (sane) atomicAdd(&cnt, 1);
  __syncthreads();
  if (t == 0) *flag = (cnt >= 192) ? 1 : 0;
}

// ---------------------------------------------------------------------------
// Convert params to canonical bf16.
// ---------------------------------------------------------------------------
#define NCANON 153988
__global__ __launch_bounds__(256) void convert_params_kernel(
    const int* __restrict__ flag,
    const void* w_qkv, const void* b_qkv, const void* w_dw, const void* b_dw,
    const void* w_proj, const void* b_proj, const void* temp,
    bf16* __restrict__ canon)
{
  const bool isbf = (*flag != 0);
  int i = blockIdx.x*256 + threadIdx.x;
  if (i >= NCANON) return;
  const void* src; int off;
  if      (i < 110592){ src = w_qkv;  off = i; }
  else if (i < 111168){ src = b_qkv;  off = i - 110592; }
  else if (i < 116352){ src = w_dw;   off = i - 111168; }
  else if (i < 116928){ src = b_dw;   off = i - 116352; }
  else if (i < 153792){ src = w_proj; off = i - 116928; }
  else if (i < 153984){ src = b_proj; off = i - 153792; }
  else                { src = temp;   off = i - 153984; }
  float v = isbf ? bf2f(((const bf16*)src)[off]) : ((const float*)src)[off];
  canon[i] = __float2bfloat16(v);
}

// ---------------------------------------------------------------------------
// Transpose X [b][192][4096] (dyn dtype) -> XT [b][4096][192] bf16 bits.
// ---------------------------------------------------------------------------
__global__ __launch_bounds__(256) void transpose_x_kernel(
    const int* __restrict__ flag, const void* __restrict__ Xv,
    short* __restrict__ XT)
{
  const bool isbf = (*flag != 0);
  __shared__ short T[64][66];
  const int c0 = blockIdx.x*64, p0 = blockIdx.y*64, b = blockIdx.z;
  const size_t xbase = (size_t)b*CCH*NP;
  #pragma unroll
  for (int s=0;s<16;s++){
    int i = threadIdx.x + s*256;
    int cc = i>>6, pp = i&63;
    size_t g = xbase + (size_t)(c0+cc)*NP + p0+pp;
    float v = isbf ? bf2f(((const bf16*)Xv)[g]) : ((const float*)Xv)[g];
    T[cc][pp] = (short)f2bfbits(v);
  }
  __syncthreads();
  #pragma unroll
  for (int s=0;s<16;s++){
    int i = threadIdx.x + s*256;
    int pl = i>>6, cl = i&63;
    XT[((size_t)b*NP + p0+pl)*CCH + c0+cl] = T[cl][pl];
  }
}

// ---------------------------------------------------------------------------
// 1x1 conv as MFMA GEMM.  Block 64o x 128p, wave = 32p x 64o.
// ---------------------------------------------------------------------------
__global__ __launch_bounds__(256) void conv1x1_mfma_kernel(
    const int* __restrict__ flag, int ydyn,
    const short* __restrict__ XT,      // [b][4096][192] bf16 bits
    const bf16* __restrict__ Wt,       // [OC][192]
    const bf16* __restrict__ bias,
    void* __restrict__ Yv, int OC)
{
  const bool yf32 = ydyn && (*flag == 0);
  __shared__ __align__(16) short Bs[2][128*32];
  const int tid = threadIdx.x, wave = tid>>6, lane = tid&63;
  const int l16 = lane&15, quad = lane>>4;
  const int o0 = blockIdx.x*64, p0 = blockIdx.y*128, b = blockIdx.z;
  const short* XTb = XT + ((size_t)b*NP + p0)*CCH;
  const short* Wb  = (const short*)Wt;

  f32x4 acc[4][2];
  #pragma unroll
  for (int mt=0;mt<4;mt++){
    #pragma unroll
    for (int r=0;r<4;r++){
      float bv = bf2f(bias[o0+mt*16+quad*4+r]);
      acc[mt][0][r]=bv; acc[mt][1][r]=bv;
    }
  }

  int4 sreg[2];
  I4B8 Afr[2][4];
  #define CLOAD(kc) { _Pragma("unroll") for (int s_=0;s_<2;s_++){ int i_=tid+256*s_; \
      sreg[s_] = *(const int4*)&XTb[(size_t)(i_>>2)*CCH + (kc)*32 + (i_&3)*8]; } }
  #define CSTORE(buf) { _Pragma("unroll") for (int s_=0;s_<2;s_++){ int i_=tid+256*s_; \
      *(int4*)&Bs[buf][(i_>>2)*32 + (i_&3)*8] = sreg[s_]; } }
  #define ALOAD(kc, buf) { _Pragma("unroll") for (int mt_=0;mt_<4;mt_++){ \
      Afr[buf][mt_].i = *(const int4*)&Wb[(size_t)(o0+mt_*16+l16)*CCH + (kc)*32 + quad*8]; } }

  CLOAD(0); CSTORE(0); ALOAD(0,0);
  __syncthreads();

  #pragma unroll
  for (int kc=0; kc<6; kc++){
    const int cur = kc&1;
    if (kc<5){ CLOAD(kc+1); ALOAD(kc+1, cur^1); }
    I4B8 Bf0, Bf1;
    Bf0.i = *(const int4*)&Bs[cur][(wave*32 + l16)*32 + quad*8];
    Bf1.i = *(const int4*)&Bs[cur][(wave*32 + 16 + l16)*32 + quad*8];
    #pragma unroll
    for (int mt=0;mt<4;mt++){
      acc[mt][0] = __builtin_amdgcn_mfma_f32_16x16x32_bf16(Afr[cur][mt].v, Bf0.v, acc[mt][0], 0,0,0);
      acc[mt][1] = __builtin_amdgcn_mfma_f32_16x16x32_bf16(Afr[cur][mt].v, Bf1.v, acc[mt][1], 0,0,0);
    }
    if (kc<5) CSTORE(cur^1);
    __syncthreads();
  }
  #undef CLOAD
  #undef CSTORE
  #undef ALOAD

  #pragma unroll
  for (int mt=0;mt<4;mt++)
    #pragma unroll
    for (int nt=0;nt<2;nt++)
      #pragma unroll
      for (int r=0;r<4;r++){
        int o = o0 + mt*16 + quad*4 + r;
        int p = p0 + wave*32 + nt*16 + l16;
        size_t off = ((size_t)b*OC + o)*NP + p;
        if (yf32) ((float*)Yv)[off] = acc[mt][nt][r];
        else      ((bf16*)Yv)[off]  = __float2bfloat16(acc[mt][nt][r]);
      }
}

// ---------------------------------------------------------------------------
// 3x3 depthwise conv, padding 1. One block per (b,ch) image.
// ---------------------------------------------------------------------------
__global__ __launch_bounds__(256) void dwconv_kernel(
    const bf16* __restrict__ in, const bf16* __restrict__ w,
    const bf16* __restrict__ bias, bf16* __restrict__ out)
{
  __shared__ __align__(16) short img[4096];
  const int bc = blockIdx.x; const int ch = bc % C3;
  const int tid = threadIdx.x;
  const int4* g4 = (const int4*)(in + (size_t)bc*NP);
  int4* s4 = (int4*)img;
  s4[tid] = g4[tid];
  s4[tid+256] = g4[tid+256];
  float wv[9];
  #pragma unroll
  for (int j=0;j<9;j++) wv[j] = bf2f(w[ch*9+j]);
  const float bv = bf2f(bias[ch]);
  __syncthreads();

  const int y = tid>>2, x0 = (tid&3)*16;
  unsigned outw[8];
  #pragma unroll
  for (int j=0;j<16;j++){
    int x = x0+j;
    float s = bv;
    #pragma unroll
    for (int ky=0;ky<3;ky++){
      int yy = y+ky-1; if (yy<0||yy>63) continue;
      const short* rp = &img[yy<<6];
      #pragma unroll
      for (int kx=0;kx<3;kx++){
        int xx = x+kx-1; if (xx<0||xx>63) continue;
        s += wv[ky*3+kx]*bfb2f(rp[xx]);
      }
    }
    unsigned hb = f2bfbits(s);
    if (j&1) outw[j>>1] |= hb<<16; else outw[j>>1] = hb;
  }
  int4* op = (int4*)((short*)out + (size_t)bc*NP + (y<<6) + x0);
  op[0] = *(int4*)&outw[0];
  op[1] = *(int4*)&outw[4];
}

// ---------------------------------------------------------------------------
// L2 normalize q (in place) and k (-> K^T [bh][n][64], zero-padded d 48..63,
// 16B-unit XOR swizzle by n&7).
// ---------------------------------------------------------------------------
__global__ __launch_bounds__(256) void l2norm_t_kernel(
    bf16* __restrict__ buf, short* __restrict__ KT)
{
  int idx = blockIdx.x*256 + threadIdx.x;   // 65536 total
  int n = idx & 4095; int t = idx >> 12;
  int head = t & 3; int qk = (t>>2)&1; int b = t>>3;
  bf16* p = buf + ((size_t)b*C3 + qk*CCH + head*HD)*NP + n;
  float v[HD];
  float ss = 0.f;
  #pragma unroll
  for (int d=0; d<HD; d++){ v[d] = bf2f(p[(size_t)d*NP]); ss += v[d]*v[d]; }
  float inv = 1.0f / fmaxf(sqrtf(ss), 1e-12f);
  if (qk == 0){
    #pragma unroll
    for (int d=0; d<HD; d++) p[(size_t)d*NP] = __float2bfloat16(v[d]*inv);
  } else {
    short* row = KT + ((size_t)(b*NH+head)*NP + n)*64;
    int sw = n & 7;
    #pragma unroll
    for (int u=0; u<8; u++){
      int4 w = {0,0,0,0};
      if (u < 6){
        int d0 = u*8;
        w.x = (unsigned)f2bfbits(v[d0+0]*inv) | ((unsigned)f2bfbits(v[d0+1]*inv)<<16);
        w.y = (unsigned)f2bfbits(v[d0+2]*inv) | ((unsigned)f2bfbits(v[d0+3]*inv)<<16);
        w.z = (unsigned)f2bfbits(v[d0+4]*inv) | ((unsigned)f2bfbits(v[d0+5]*inv)<<16);
        w.w = (unsigned)f2bfbits(v[d0+6]*inv) | ((unsigned)f2bfbits(v[d0+7]*inv)<<16);
      }
      *(int4*)&row[(u^sw)*8] = w;
    }
  }
}

// ---------------------------------------------------------------------------
// Flash attention, mfma_f32_16x16x32_bf16, K chunk 128, dbuf, 1 barrier/iter.
// Fixed-max softmax: q,k unit vectors => a = sc*(q.k) in [-|sc|,|sc|], so
// p = exp2(a - |sc|) <= 1 never overflows: NO running max, NO O-rescale,
// NO in-loop cross-lane reductions. l = per-lane partials, reduced once at
// the end (4 shfls total). Writes O^T [b][n][192].
// ---------------------------------------------------------------------------
__global__ __launch_bounds__(256) void flash_kernel(
    const bf16* __restrict__ qkv,      // bufB [b][c3][n]
    const short* __restrict__ KT,      // [bh][n][64] swizzled bf16 bits
    const bf16* __restrict__ temp,
    short* __restrict__ OT)            // [b][4096][192] bf16 bits
{
  __shared__ __align__(16) short Ks[2][128*64];
  __shared__ __align__(16) short Vs[2][48*136];
  __shared__ __align__(16) short Ps[4][16*136];

  const int bh = blockIdx.x, b = bh>>2, head = bh&3;
  const int q0 = blockIdx.y * 64;
  const int tid = threadIdx.x, wave = tid>>6, lane = tid&63;
  const int l16 = lane&15, quad = lane>>4;

  const unsigned short* Qp = (const unsigned short*)(qkv + ((size_t)b*C3 + head*HD)*NP)
                             + q0 + wave*16 + l16;
  const short* Vp = (const short*)(qkv + ((size_t)b*C3 + 2*CCH + head*HD)*NP);
  const short* KTs = KT + (size_t)bh*NP*64;
  const float sc = bf2f(temp[head]) * 1.44269504f;
  const float negM = -__builtin_fabsf(sc);       // fixed softmax shift

  I4B8 A0, A1;
  {
    unsigned q0b[8];
    #pragma unroll
    for (int j=0;j<8;j++) q0b[j] = Qp[(size_t)(quad*8+j)*NP];
    A0.i.x = q0b[0] | (q0b[1]<<16); A0.i.y = q0b[2] | (q0b[3]<<16);
    A0.i.z = q0b[4] | (q0b[5]<<16); A0.i.w = q0b[6] | (q0b[7]<<16);
    if (quad < 2){
      unsigned q1b[8];
      #pragma unroll
      for (int j=0;j<8;j++) q1b[j] = Qp[(size_t)(32+quad*8+j)*NP];
      A1.i.x = q1b[0] | (q1b[1]<<16); A1.i.y = q1b[2] | (q1b[3]<<16);
      A1.i.z = q1b[4] | (q1b[5]<<16); A1.i.w = q1b[6] | (q1b[7]<<16);
    } else {
      A1.i.x = 0; A1.i.y = 0; A1.i.z = 0; A1.i.w = 0;
    }
  }

  f32x4 O0 = {0,0,0,0}, O1 = {0,0,0,0}, O2 = {0,0,0,0};
  float rs[4] = {0.f, 0.f, 0.f, 0.f};    // per-lane partial row sums
  short* Pw = Ps[wave];
  const int sw = l16 & 7;

  int4 kreg[4], vreg[3];
  #define KLOAD(CHUNK) { const int k0_=(CHUNK)<<7; \
    const int4* gk_ = (const int4*)(KTs + (size_t)k0_*64); \
    _Pragma("unroll") for (int s_=0;s_<4;s_++) kreg[s_] = gk_[tid + 256*s_]; \
    _Pragma("unroll") for (int s_=0;s_<3;s_++){ int i_=tid+256*s_; \
      vreg[s_] = *(const int4*)(Vp + (size_t)(i_>>4)*NP + k0_ + (i_&15)*8); } }
  #define KSTORE(BUFI) { int4* lk_ = (int4*)&Ks[BUFI][0]; \
    _Pragma("unroll") for (int s_=0;s_<4;s_++) lk_[tid+256*s_] = kreg[s_]; \
    _Pragma("unroll") for (int s_=0;s_<3;s_++){ int i_=tid+256*s_; \
      *(int4*)&Vs[BUFI][(i_>>4)*136 + (i_&15)*8] = vreg[s_]; } }

  KLOAD(0); KSTORE(0);
  __syncthreads();

  for (int t=0; t<32; ++t){
    const int cur = t & 1;
    if (t < 31) KLOAD(t+1);

    const short* Kb = &Ks[cur][0];
    const short* Vb = &Vs[cur][0];

    f32x4 S[8];
    #pragma unroll
    for (int ct=0; ct<8; ++ct){
      const int row = (ct*16 + l16)*64;
      I4B8 B0, B1;
      B0.i = *(const int4*)&Kb[row + ((quad^sw)*8)];
      B1.i = *(const int4*)&Kb[row + (((4+quad)^sw)*8)];
      f32x4 z = {0,0,0,0};
      z = __builtin_amdgcn_mfma_f32_16x16x32_bf16(A0.v, B0.v, z, 0,0,0);
      z = __builtin_amdgcn_mfma_f32_16x16x32_bf16(A1.v, B1.v, z, 0,0,0);
      S[ct] = z;
    }

    // fixed-max softmax: no cross-lane ops, no rescale
    #pragma unroll
    for (int r=0;r<4;r++){
      float acc0 = 0.f, acc1 = 0.f;
      #pragma unroll
      for (int ct=0;ct<8;ct++){
        float p = __builtin_amdgcn_exp2f(__builtin_fmaf(S[ct][r], sc, negM));
        if (ct & 1) acc1 += p; else acc0 += p;
        Pw[(quad*4+r)*136 + ct*16 + l16] = (short)f2bfbits(p);
      }
      rs[r] += acc0 + acc1;
    }

    #pragma unroll
    for (int c=0;c<4;c++){
      I4B8 AP, BV0, BV1, BV2;
      AP.i  = *(const int4*)&Pw[l16*136 + c*32 + quad*8];
      BV0.i = *(const int4*)&Vb[(l16   )*136 + c*32 + quad*8];
      BV1.i = *(const int4*)&Vb[(16+l16)*136 + c*32 + quad*8];
      BV2.i = *(const int4*)&Vb[(32+l16)*136 + c*32 + quad*8];
      O0 = __builtin_amdgcn_mfma_f32_16x16x32_bf16(AP.v, BV0.v, O0, 0,0,0);
      O1 = __builtin_amdgcn_mfma_f32_16x16x32_bf16(AP.v, BV1.v, O1, 0,0,0);
      O2 = __builtin_amdgcn_mfma_f32_16x16x32_bf16(AP.v, BV2.v, O2, 0,0,0);
    }

    if (t < 31) KSTORE(cur^1);
    __syncthreads();
  }
  #undef KLOAD
  #undef KSTORE

  // one-time l reduction (16 lanes of each quad hold partials of its 4 rows)
  float l[4];
  #pragma unroll
  for (int r=0;r<4;r++){
    float v = rs[r];
    v += __shfl_xor(v,1);
    v += __shfl_xor(v,2);
    v += __shfl_xor(v,4);
    v += __shfl_xor(v,8);
    l[r] = v;
  }

  // O^T epilogue: row = query position, cols = head*48 + d
  #pragma unroll
  for (int r=0;r<4;r++){
    float invl = 1.0f / l[r];
    short* row = OT + ((size_t)b*NP + q0 + wave*16 + quad*4 + r)*CCH + head*HD;
    row[l16]    = (short)f2bfbits(O0[r]*invl);
    row[16+l16] = (short)f2bfbits(O1[r]*invl);
    row[32+l16] = (short)f2bfbits(O2[r]*invl);
  }
}

// ---------------------------------------------------------------------------
extern "C" void kernel_launch(void* const* d_in, const int* in_sizes, int n_in,
                              void* d_out, int out_size, void* d_ws, size_t ws_size,
                              hipStream_t stream)
{
  // ws layout (bytes) — 19.2 MB footprint proven since R3:
  //   [0]        int flag
  //   [16]       bf16 canon[153988]
  //   [308096]   bf16 bufA[2*576*4096]  (O^T head; K^T at el 1572864)
  //   [9745280]  bf16 bufB[2*576*4096]  (X^T borrows head pre-dwconv)
  int*  flag  = (int*)d_ws;
  bf16* canon = (bf16*)((char*)d_ws + 16);
  bf16* bufA  = (bf16*)((char*)d_ws + 308096);
  bf16* bufB  = (bf16*)((char*)d_ws + 9745280);
  short* XT = (short*)bufB;
  short* OT = (short*)bufA;
  short* KT = (short*)(bufA + 1572864);

  bf16* cw_qkv  = canon;
  bf16* cb_qkv  = canon + 110592;
  bf16* cw_dw   = canon + 111168;
  bf16* cb_dw   = canon + 116352;
  bf16* cw_proj = canon + 116928;
  bf16* cb_proj = canon + 153792;
  bf16* ctemp   = canon + 153984;

  probe_kernel<<<1, 256, 0, stream>>>((const unsigned*)d_in[0], flag);
  convert_params_kernel<<<602, 256, 0, stream>>>(flag,
      d_in[1], d_in[2], d_in[3], d_in[4], d_in[5], d_in[6], d_in[7], canon);
  transpose_x_kernel<<<dim3(3,64,2), 256, 0, stream>>>(flag, d_in[0], XT);
  conv1x1_mfma_kernel<<<dim3(9,32,2), 256, 0, stream>>>(flag, 0,
      XT, cw_qkv, cb_qkv, bufA, C3);
  dwconv_kernel<<<dim3(BB*C3), 256, 0, stream>>>(bufA, cw_dw, cb_dw, bufB);
  l2norm_t_kernel<<<dim3(256), 256, 0, stream>>>(bufB, KT);
  flash_kernel<<<dim3(8,64), 256, 0, stream>>>(bufB, KT, ctemp, OT);
  conv1x1_mfma_kernel<<<dim3(3,32,2), 256, 0, stream>>>(flag, 1,
      OT, cw_proj, cb_proj, d_out, CCH);
}